// Round 7
// baseline (750.849 us; speedup 1.0000x reference)
//
#include <hip/hip_runtime.h>
#include <math.h>
#include <stdint.h>

typedef _Float16 f16;
typedef _Float16 f16x8 __attribute__((ext_vector_type(8)));
typedef float f32x4 __attribute__((ext_vector_type(4)));

#define B_    16
#define T_    4096
#define SEM   512
#define ACO   32
#define XROWS 544
#define CODES 2048
#define EPSC  1e-5f
#define HALFC 4.0f
#define ECLAMP 60000.0f

// ---- ws layout (float units) ----
// embT   [0, 1048576)              fp32 [512][2048] for finalize gather
// bias   [1048576, 1050624)        0.5*|e|^2
// codesW [1050624, 1116160)        int[65536]
// EhT    [1116160, 1640448)        f16[2048][512] (high half)
// ElT    [1640448, 2164736)        f16[2048][512] (low half)
//
// X hi/lo planes live in the OUTPUT buffer as scratch (finalize overwrites
// them only after argmin has consumed them):
// XhT = out[0, 16777216)  floats   = f16[65536][512]
// XlT = out[16777216, 33554432)    = f16[65536][512]   (QOFF = 35651584 > end)

// ============ kernel 1: per-code bias = 0.5*|e|^2 ============
__global__ void bias_kernel(const float* __restrict__ esum,
                            const float* __restrict__ usage,
                            float* __restrict__ bias) {
    int c = blockIdx.x;
    float u = fmaxf(usage[c], EPSC);
    float s = 0.f;
    for (int d = threadIdx.x; d < SEM; d += 64) {
        float v = esum[(size_t)c * SEM + d] / u;
        s += v * v;
    }
    for (int off = 32; off; off >>= 1) s += __shfl_down(s, off);
    if (threadIdx.x == 0) bias[c] = 0.5f * s;
}

// ============ kernel 2: embT[d][c] = esum[c][d] / clip(usage[c]) ============
__global__ void embT_kernel(const float* __restrict__ esum,
                            const float* __restrict__ usage,
                            float* __restrict__ embT) {
    __shared__ float tile[32][33];
    int c0 = blockIdx.x * 32;
    int d0 = blockIdx.y * 32;
    int col = threadIdx.x & 31, r = threadIdx.x >> 5;  // 256 threads: r=0..7
    for (int i = r; i < 32; i += 8) {
        float u = fmaxf(usage[c0 + i], EPSC);
        tile[col][i] = esum[(size_t)(c0 + i) * SEM + d0 + col] / u;
    }
    __syncthreads();
    for (int i = r; i < 32; i += 8)
        embT[(size_t)(d0 + i) * CODES + c0 + col] = tile[i][col];
}

// ============ kernel 3: f16 hi/lo split planes of emb, [c][d] layout ============
__global__ void esplit_kernel(const float* __restrict__ esum,
                              const float* __restrict__ usage,
                              f16* __restrict__ EhT, f16* __restrict__ ElT) {
    int c = blockIdx.x;
    float u = fmaxf(usage[c], EPSC);
    for (int d = threadIdx.x; d < SEM; d += 256) {
        float e = esum[(size_t)c * SEM + d] / u;
        e = fminf(fmaxf(e, -ECLAMP), ECLAMP);
        f16 h = (f16)e;
        EhT[(size_t)c * SEM + d] = h;
        ElT[(size_t)c * SEM + d] = (f16)(e - (float)h);
    }
}

// ============ kernel 3b: transpose+split x -> XhT/XlT [m][k] f16 ============
__global__ void xsplit_kernel(const float* __restrict__ x,
                              f16* __restrict__ XhT, f16* __restrict__ XlT) {
    int m0 = blockIdx.x * 256;
    int d0 = blockIdx.y * 32;
    int b  = m0 >> 12;
    int t  = (m0 & 4095) + (int)threadIdx.x;
    const float* xp = x + ((size_t)b * XROWS + d0) * T_ + t;
    int m = m0 + (int)threadIdx.x;

    f16x8 hv[4], lv[4];
#pragma unroll
    for (int j = 0; j < 4; j++) {
#pragma unroll
        for (int e = 0; e < 8; e++) {
            float v = xp[(size_t)(j * 8 + e) * T_];
            f16 h = (f16)v;
            hv[j][e] = h;
            lv[j][e] = (f16)(v - (float)h);
        }
    }
    f16* oh = XhT + (size_t)m * SEM + d0;
    f16* ol = XlT + (size_t)m * SEM + d0;
#pragma unroll
    for (int j = 0; j < 4; j++) {
        *(f16x8*)(oh + j * 8) = hv[j];
        *(f16x8*)(ol + j * 8) = lv[j];
    }
}

// ============ kernel 4: MFMA GEMM + fused argmin ============
// 256 threads (4 waves = 2M x 2N), MB=128 m-rows, full N=2048 per block via
// 8 nc-chunks of 256 codes. SINGLE 48 KB LDS buffer -> 2 independent blocks
// per CU (grid 512 = 2 x 256 CUs): when one block sits in its
// STAGE->vmcnt(0)->barrier window, the co-resident block's waves feed the
// MFMA pipe (m114 co-scheduling). Per-wave tile stays 64m x 128n (acc[4][8],
// MFMA:ds_read ratio 4). T2 source+read XOR swizzle kept (conflicts = 0).
// R5 bugfix: X planes are 512 chunks each (128 rows), staged in TWO passes
// (off = tid and tid+256); R5's single pass left rows 64..127 unstaged.
#define MB   128
#define NCB  256
#define BK   32
#define NTH  256
#define NCHN (CODES / NCB)     // 8
#define KT   (SEM / BK)        // 16
// LDS plane bases (f16 units): Xh 0, Xl 4096, Eh 8192, El 16384; total 24576
#define XHB  0
#define XLB  4096
#define EHB  8192
#define ELB  16384

__device__ __forceinline__ void gl_lds16(const f16* g, f16* l) {
    __builtin_amdgcn_global_load_lds(
        (const __attribute__((address_space(1))) unsigned int*)(g),
        (__attribute__((address_space(3))) unsigned int*)(l),
        16, 0, 0);
}

__global__ __launch_bounds__(NTH, 2) void argmin_mfma(
        const f16* __restrict__ XhT, const f16* __restrict__ XlT,
        const f16* __restrict__ EhT, const f16* __restrict__ ElT,
        const float* __restrict__ bias,
        int* __restrict__ codesW, float* __restrict__ codes_out) {
    __shared__ __align__(16) f16 smem[24576];   // 48 KB

    int tid = threadIdx.x;
    int w   = tid >> 6;        // wave 0..3
    int l   = tid & 63;
    int q   = l >> 4;          // quad
    int r16 = l & 15;
    int wm  = w >> 1;          // 0..1  (m-tile of 64)
    int wn  = w & 1;           // 0..1  (n-half of 128)

    int m0 = blockIdx.x * MB;

    // swizzled GLOBAL source column for STAGE: chunk ch=tid&3, row key (tid>>3)&3
    // valid for any dest off = k*256 + tid (row steps of 64 keep (row>>1)&3)
    int scz = (((tid & 3) ^ ((tid >> 3) & 3))) * 8;
    // swizzled read chunk: q' = q ^ ((row>>1)&3) = q ^ ((r16>>1)&3)
    int qs8 = (q ^ ((r16 >> 1) & 3)) * 8;

    float bestS[16];
    int   bestI[16];
#pragma unroll
    for (int i = 0; i < 16; i++) { bestS[i] = -3.4e38f; bestI[i] = 0; }

    f32x4 acc[4][8];
#pragma unroll
    for (int mi = 0; mi < 4; mi++)
#pragma unroll
        for (int ni = 0; ni < 8; ni++)
            acc[mi][ni] = (f32x4){0.f, 0.f, 0.f, 0.f};

    // STAGE: 3072 x 16B chunks, 12 per thread.
    // X planes: 512 chunks each -> 2 passes x 2 planes
    // E planes: 1024 chunks each -> 2 passes x (2 planes x 2 halves)
#define STAGE(NB, KK) do {                                                  \
    _Pragma("unroll")                                                       \
    for (int ii = 0; ii < 2; ii++) {                                        \
        int offx = ii * 256 + tid;                                          \
        int mm = offx >> 2;                                                 \
        size_t gx = (size_t)(m0 + mm) * SEM + (KK) + scz;                   \
        gl_lds16(XhT + gx, smem + XHB + offx * 8);                          \
        gl_lds16(XlT + gx, smem + XLB + offx * 8);                          \
        int off = ii * 256 + tid;                                           \
        int nn = off >> 2;                                                  \
        size_t ge = (size_t)((NB) + nn) * SEM + (KK) + scz;                 \
        gl_lds16(EhT + ge, smem + EHB + off * 8);                           \
        gl_lds16(ElT + ge, smem + ELB + off * 8);                           \
        int off2 = off + 512;                                               \
        int nn2 = off2 >> 2;                                                \
        size_t ge2 = (size_t)((NB) + nn2) * SEM + (KK) + scz;               \
        gl_lds16(EhT + ge2, smem + EHB + off2 * 8);                         \
        gl_lds16(ElT + ge2, smem + ELB + off2 * 8);                         \
    }                                                                       \
} while (0)

    for (int t = 0; t < NCHN * KT; t++) {
        int nbase = (t >> 4) * NCB;

        STAGE(nbase, (t & 15) * BK);
        __syncthreads();   // vmcnt(0): staged tile visible to all waves

        // compute (reads use swizzled chunk qs8)
        f16x8 ah[4], al[4];
#pragma unroll
        for (int mi = 0; mi < 4; mi++) {
            int ao = (wm * 64 + mi * 16 + r16) * 32 + qs8;
            ah[mi] = *(const f16x8*)&smem[XHB + ao];
            al[mi] = *(const f16x8*)&smem[XLB + ao];
        }
#pragma unroll
        for (int ni = 0; ni < 8; ni++) {
            int bo = (wn * 128 + ni * 16 + r16) * 32 + qs8;
            f16x8 bh = *(const f16x8*)&smem[EHB + bo];
            f16x8 bl = *(const f16x8*)&smem[ELB + bo];
#pragma unroll
            for (int mi = 0; mi < 4; mi++) {
                f32x4 a0 = acc[mi][ni];
                a0 = __builtin_amdgcn_mfma_f32_16x16x32_f16(al[mi], bh, a0, 0, 0, 0);
                a0 = __builtin_amdgcn_mfma_f32_16x16x32_f16(ah[mi], bl, a0, 0, 0, 0);
                a0 = __builtin_amdgcn_mfma_f32_16x16x32_f16(ah[mi], bh, a0, 0, 0, 0);
                acc[mi][ni] = a0;
            }
        }

        // end of an nc-chunk: fold bias, update best, reset acc
        if ((t & 15) == 15) {
#pragma unroll
            for (int ni = 0; ni < 8; ni++) {
                int n = nbase + wn * 128 + ni * 16 + r16;
                float bb = bias[n];
#pragma unroll
                for (int mi = 0; mi < 4; mi++)
#pragma unroll
                    for (int reg = 0; reg < 4; reg++) {
                        float s = acc[mi][ni][reg] - bb;
                        int slot = mi * 4 + reg;
                        if (s > bestS[slot]) { bestS[slot] = s; bestI[slot] = n; }
                        acc[mi][ni][reg] = 0.f;
                    }
            }
        }
        __syncthreads();   // all reads done before next STAGE overwrites
    }

    // reduce across the 16 column-lanes (bits 0..3), tie -> smallest idx
#pragma unroll
    for (int mask = 1; mask < 16; mask <<= 1) {
#pragma unroll
        for (int slot = 0; slot < 16; slot++) {
            float os = __shfl_xor(bestS[slot], mask);
            int   oi = __shfl_xor(bestI[slot], mask);
            if (os > bestS[slot] || (os == bestS[slot] && oi < bestI[slot])) {
                bestS[slot] = os; bestI[slot] = oi;
            }
        }
    }

    // ---- cross-wave merge: wave (wm, wn=1) -> wave (wm, wn=0) via LDS ----
    // smem is dead here (all waves past the final loop barrier).
    {
        float* sMS = (float*)smem;              // [4 waves][4 q][16 slots]
        int*   sMI = (int*)(sMS + 4 * 4 * 16);
        if (r16 == 0) {
            int base = (w * 4 + q) * 16;
#pragma unroll
            for (int slot = 0; slot < 16; slot++) {
                sMS[base + slot] = bestS[slot];
                sMI[base + slot] = bestI[slot];
            }
        }
        __syncthreads();
        if (wn == 0 && r16 == 0) {
            int pbase = ((w + 1) * 4 + q) * 16;
#pragma unroll
            for (int slot = 0; slot < 16; slot++) {
                float os = sMS[pbase + slot];
                int   oi = sMI[pbase + slot];
                if (os > bestS[slot] || (os == bestS[slot] && oi < bestI[slot])) {
                    bestS[slot] = os; bestI[slot] = oi;
                }
            }
#pragma unroll
            for (int mi = 0; mi < 4; mi++)
#pragma unroll
                for (int reg = 0; reg < 4; reg++) {
                    int m = m0 + wm * 64 + mi * 16 + q * 4 + reg;
                    int bi = bestI[mi * 4 + reg];
                    codesW[m] = bi;
                    int bb2 = m >> 12, tt = m & 4095;
                    codes_out[(size_t)bb2 * 33 * T_ + tt] = (float)bi;
                }
        }
    }
#undef STAGE
}

// ============ kernel 6: finalize (sem select/gather + aco path) ============
__global__ void finalize_kernel(const float* __restrict__ x,
                                const float* __restrict__ embT,
                                const int* __restrict__ codes_ws,
                                const float* __restrict__ noise,
                                const float* __restrict__ probs_sem,
                                const float* __restrict__ probs_aco,
                                float* __restrict__ out,
                                float* __restrict__ codes_out) {
    const size_t N0 = (size_t)B_ * SEM * T_;   // 33,554,432
    const size_t N1 = (size_t)B_ * ACO * T_;   // 2,097,152
    size_t idx = (size_t)blockIdx.x * 256 + threadIdx.x;
    if (idx < N0) {
        int t = (int)(idx & 4095);
        int d = (int)((idx >> 12) & 511);
        int b = (int)(idx >> 21);
        float v;
        if (probs_sem[b] < 0.5f) {
            int c = codes_ws[(b << 12) + t];
            v = embT[(size_t)d * CODES + c];
        } else {
            v = x[((size_t)(b * XROWS + d)) * T_ + t];
        }
        out[((size_t)(b * XROWS + d)) * T_ + t] = v;
    } else if (idx < N0 + N1) {
        size_t i2 = idx - N0;
        int t = (int)(i2 & 4095);
        int j = (int)((i2 >> 12) & 31);
        int b = (int)(i2 >> 17);
        float a  = x[((size_t)(b * XROWS + SEM + j)) * T_ + t];
        float zb = tanhf(a) * HALFC;
        float p  = probs_aco[b];
        float zo;
        if (p < 0.5f) {
            zo = rintf(zb);                         // round-half-even, matches jnp.round
        } else if (p < 0.75f) {
            float nz = noise[((size_t)(b * ACO + j)) * T_ + t];
            float ns = ((nz * 2.0f - 1.0f) * (float)(1.0 / 9.0)) * HALFC;
            zo = fminf(fmaxf(zb + ns, -HALFC), HALFC);
        } else {
            zo = zb;
        }
        float code = fminf(fmaxf(rintf(zo + HALFC), 0.f), 8.f);
        out[((size_t)(b * XROWS + SEM + j)) * T_ + t] = zo * 0.25f;
        codes_out[((size_t)(b * 33 + 1 + j)) * T_ + t] = code;
    }
}

extern "C" void kernel_launch(void* const* d_in, const int* in_sizes, int n_in,
                              void* d_out, int out_size, void* d_ws, size_t ws_size,
                              hipStream_t stream) {
    const float* x      = (const float*)d_in[0];
    const float* esum   = (const float*)d_in[1];
    const float* usage  = (const float*)d_in[2];
    const float* noise  = (const float*)d_in[3];
    const float* psem   = (const float*)d_in[4];
    const float* paco   = (const float*)d_in[5];
    float* out = (float*)d_out;

    float* wsf    = (float*)d_ws;
    float* embT   = wsf;
    float* bias   = wsf + 1048576;
    int*   codesW = (int*)(wsf + 1050624);
    f16*   EhT    = (f16*)(wsf + 1116160);
    f16*   ElT    = (f16*)(wsf + 1640448);

    const size_t QOFF = (size_t)B_ * XROWS * T_;   // 35,651,584
    float* codes_out = out + QOFF;

    // X hi/lo scratch inside the output buffer (consumed before finalize writes)
    f16* XhT = (f16*)out;                    // 64 MB
    f16* XlT = (f16*)(out + 16777216);       // 64 MB, ends at 33,554,432 < QOFF

    xsplit_kernel<<<dim3((B_ * T_) / 256, SEM / 32), 256, 0, stream>>>(x, XhT, XlT);
    bias_kernel<<<CODES, 64, 0, stream>>>(esum, usage, bias);
    embT_kernel<<<dim3(CODES / 32, SEM / 32), 256, 0, stream>>>(esum, usage, embT);
    esplit_kernel<<<CODES, 256, 0, stream>>>(esum, usage, EhT, ElT);
    argmin_mfma<<<(B_ * T_) / MB, NTH, 0, stream>>>(XhT, XlT, EhT, ElT, bias,
                                                    codesW, codes_out);
    const size_t NTOT = (size_t)B_ * SEM * T_ + (size_t)B_ * ACO * T_;
    finalize_kernel<<<(int)(NTOT / 256), 256, 0, stream>>>(x, embT, codesW, noise,
                                                           psem, paco, out, codes_out);
}